// Round 3
// baseline (658.845 us; speedup 1.0000x reference)
//
#include <hip/hip_runtime.h>

#define NT 32
#define EPSF 1e-8f

// ================= Gram kernel =================
// G = vecs @ vecs^T, vecs (32, D) fp32 row-major.
// Staging: lane l owns column (base+l); loads its 32 row values as scalar
// dwords (coalesced 256B/instr across lanes), writes 8x ds_write_b128 into a
// swizzled column-major LDS tile: addr(r, j) = j*32 + ((r>>2) ^ (j&7))*4 + (r&3).
// Writes hit all 8 bank phases (conflict-free, verified: SQ_LDS_BANK_CONFLICT=0);
// compute reads are broadcast/2-way (free). Lane (cj,pi,pk) accumulates an 8x8
// patch with cj splitting tile columns 4-ways; no barrier in K-loop
// (wave-private tile, per-wave DS ops in-order).
// __launch_bounds__(256,2): round-1 evidence -> 128 VGPR, NO spill. (256,4)
// forced 64 VGPR and spilled ~600MB of scratch (round-2 regression).
#define TILE_COLS 64
#define GR_THREADS 256
#define WAVES_PB 4
#define TILES_PW 8    // cols/wave = 512, cols/block = 2048 -> grid = 1024

__global__ __launch_bounds__(GR_THREADS, 2)
void gram_kernel(const float* __restrict__ vecs, double* __restrict__ Gd, int D)
{
    __shared__ __align__(16) float tile[WAVES_PB][TILE_COLS * 32];
    __shared__ float Gpart[NT * NT];

    const int tid  = threadIdx.x;
    const int wave = tid >> 6;
    const int lane = tid & 63;

    for (int e = tid; e < NT * NT; e += GR_THREADS) Gpart[e] = 0.0f;
    __syncthreads();

    float* my = tile[wave];
    const int swz = lane & 7;

    const int cj = lane >> 4;        // column subgroup 0..3
    const int pi = (lane >> 2) & 3;  // patch rows 8*pi..
    const int pk = lane & 3;         // patch cols 8*pk..

    float acc[8][8];
#pragma unroll
    for (int r = 0; r < 8; r++)
#pragma unroll
        for (int c = 0; c < 8; c++) acc[r][c] = 0.0f;

    const long base0 = (long)blockIdx.x * (WAVES_PB * TILES_PW * TILE_COLS)
                     + (long)wave * (TILES_PW * TILE_COLS) + lane;

    float pre[32];
#pragma unroll
    for (int r = 0; r < 32; r++) pre[r] = vecs[(long)r * D + base0];

    for (int t = 0; t < TILES_PW; t++) {
        // stage tile t: 8 contiguous b128 writes per lane, swizzled chunks
#pragma unroll
        for (int rg = 0; rg < 8; rg++) {
            float4 w = make_float4(pre[4 * rg], pre[4 * rg + 1],
                                   pre[4 * rg + 2], pre[4 * rg + 3]);
            *(float4*)(my + lane * 32 + ((rg ^ swz) << 2)) = w;
        }
        // prefetch tile t+1 (flies during compute below)
        if (t + 1 < TILES_PW) {
            const long b = base0 + (long)(t + 1) * TILE_COLS;
#pragma unroll
            for (int r = 0; r < 32; r++) pre[r] = vecs[(long)r * D + b];
        }
#pragma unroll
        for (int jt = 0; jt < 16; jt++) {
            const int j = (jt << 2) + cj;
            const float* col = my + j * 32;
            const int js = j & 7;
            const float4 a0 = *(const float4*)(col + (((2 * pi) ^ js) << 2));
            const float4 a1 = *(const float4*)(col + (((2 * pi + 1) ^ js) << 2));
            const float4 b0 = *(const float4*)(col + (((2 * pk) ^ js) << 2));
            const float4 b1 = *(const float4*)(col + (((2 * pk + 1) ^ js) << 2));
            const float a[8] = {a0.x, a0.y, a0.z, a0.w, a1.x, a1.y, a1.z, a1.w};
            const float b[8] = {b0.x, b0.y, b0.z, b0.w, b1.x, b1.y, b1.z, b1.w};
#pragma unroll
            for (int r = 0; r < 8; r++)
#pragma unroll
                for (int c = 0; c < 8; c++)
                    acc[r][c] = fmaf(a[r], b[c], acc[r][c]);
        }
    }

    // fold the cj column-split (lanes sharing lane&15 share a patch)
#pragma unroll
    for (int r = 0; r < 8; r++)
#pragma unroll
        for (int c = 0; c < 8; c++) {
            float v = acc[r][c];
            v += __shfl_xor(v, 16);
            v += __shfl_xor(v, 32);
            if (lane < 16)
                atomicAdd(&Gpart[(8 * pi + r) * NT + (8 * pk + c)], v);
        }
    __syncthreads();
    for (int e = tid; e < NT * NT; e += GR_THREADS)
        atomicAdd(&Gd[e], (double)Gpart[e]);
}

// ================= Solver kernel =================
// All hot-loop cross-lane ops are DPP / v_readlane (VALU/SALU speed).
// ZERO ds_* and zero __ballot in the iteration.
template<int CTRL>
__device__ __forceinline__ float dpp0(float x) {  // invalid source lanes -> 0
    return __int_as_float(__builtin_amdgcn_update_dpp(
        0, __float_as_int(x), CTRL, 0xF, 0xF, true));
}
template<int CTRL>
__device__ __forceinline__ float dppk(float oldv, float x) {  // invalid -> oldv
    return __int_as_float(__builtin_amdgcn_update_dpp(
        __float_as_int(oldv), __float_as_int(x), CTRL, 0xF, 0xF, false));
}
__device__ __forceinline__ float rdlane(float x, int l) {
    return __int_as_float(__builtin_amdgcn_readlane(__float_as_int(x), l));
}
__device__ __forceinline__ unsigned long long rdlane64(unsigned long long x, int l) {
    int lo = __builtin_amdgcn_readlane((int)(unsigned int)x, l);
    int hi = __builtin_amdgcn_readlane((int)(unsigned int)(x >> 32), l);
    return ((unsigned long long)(unsigned int)hi << 32) | (unsigned int)lo;
}
template<int CTRL>
__device__ __forceinline__ unsigned long long dpp64k(unsigned long long x) {
    int lo = (int)(unsigned int)x, hi = (int)(unsigned int)(x >> 32);
    int plo = __builtin_amdgcn_update_dpp(lo, lo, CTRL, 0xF, 0xF, false);
    int phi = __builtin_amdgcn_update_dpp(hi, hi, CTRL, 0xF, 0xF, false);
    return ((unsigned long long)(unsigned int)phi << 32) | (unsigned int)plo;
}

// sum over lanes 0..31, uniform result
__device__ __forceinline__ float bsum32u(float v) {
    v += dpp0<0x111>(v);  // row_shr:1
    v += dpp0<0x112>(v);  // row_shr:2
    v += dpp0<0x114>(v);  // row_shr:4
    v += dpp0<0x118>(v);  // row_shr:8
    return rdlane(v, 15) + rdlane(v, 31);
}
__device__ __forceinline__ float bmin32u(float v) {
    v = fminf(v, dppk<0x111>(v, v));
    v = fminf(v, dppk<0x112>(v, v));
    v = fminf(v, dppk<0x114>(v, v));
    v = fminf(v, dppk<0x118>(v, v));
    return fminf(rdlane(v, 15), rdlane(v, 31));
}
// min over lanes 0..31 of a packed u64, uniform result
__device__ __forceinline__ unsigned long long bminu64(unsigned long long P) {
    { unsigned long long q = dpp64k<0x111>(P); P = (q < P) ? q : P; }
    { unsigned long long q = dpp64k<0x112>(P); P = (q < P) ? q : P; }
    { unsigned long long q = dpp64k<0x114>(P); P = (q < P) ? q : P; }
    { unsigned long long q = dpp64k<0x118>(P); P = (q < P) ? q : P; }
    unsigned long long a = rdlane64(P, 0);   // min of lanes 0..15
    unsigned long long b = rdlane64(P, 16);  // min of lanes 16..31
    return (a < b) ? a : b;
}

__global__ __launch_bounds__(64)
void solver_kernel(const double* __restrict__ Gd, float* __restrict__ out)
{
    __shared__ float Gsh[NT * 33];
    const int lane = threadIdx.x;  // one wave

    for (int t2 = 0; t2 < 16; t2++) {
        int e = t2 * 64 + lane;
        Gsh[(e >> 5) * 33 + (e & 31)] = (float)Gd[e];
    }
    __syncthreads();

    float Grow[NT];
#pragma unroll
    for (int k = 0; k < NT; k++)
        Grow[k] = (lane < NT) ? Gsh[lane * 33 + k] : 0.0f;

    // ---- planar init: argmin over all 496 (a<b) pairs ----
    float bestCost = INFINITY, bestGamma = 0.0f;
    int bestEnc = 0x7FFFFFFF;
    for (int a = 0; a < NT - 1; a++) {
        int b = a + 1 + lane;
        if (b < NT) {
            float v11 = Gsh[a * 33 + a];
            float v12 = Gsh[a * 33 + b];
            float v22 = Gsh[b * 33 + b];
            float g = (v22 - v12) / (v11 + v22 - 2.0f * v12 + EPSF);
            float c = v22 + g * (v12 - v22);
            float gamma = (v12 >= v22) ? 0.0f : g;
            float cost  = (v12 >= v22) ? v22 : c;
            if (v12 >= v11) { gamma = 1.0f; cost = v11; }
            int enc = a * NT + b;
            if (cost < bestCost) { bestCost = cost; bestEnc = enc; bestGamma = gamma; }
        }
    }
#pragma unroll
    for (int m = 1; m < 64; m <<= 1) {
        float oc = __shfl_xor(bestCost, m);
        int   oe = __shfl_xor(bestEnc, m);
        float og = __shfl_xor(bestGamma, m);
        if (oc < bestCost || (oc == bestCost && oe < bestEnc)) {
            bestCost = oc; bestEnc = oe; bestGamma = og;
        }
    }
    const int bi = bestEnc >> 5, bj = bestEnc & 31;

    float sol = 0.0f;
    if (lane == bi) sol = bestGamma;
    if (lane == bj) sol = 1.0f - bestGamma;

    for (int it = 0; it < 250; it++) {
        // Gsol = G @ sol via readlane broadcasts
        float s0 = 0, s1 = 0, s2 = 0, s3 = 0;
#pragma unroll
        for (int k = 0; k < NT; k += 4) {
            s0 = fmaf(Grow[k + 0], rdlane(sol, k + 0), s0);
            s1 = fmaf(Grow[k + 1], rdlane(sol, k + 1), s1);
            s2 = fmaf(Grow[k + 2], rdlane(sol, k + 2), s2);
            s3 = fmaf(Grow[k + 3], rdlane(sol, k + 3), s3);
        }
        float Gsol = (s0 + s1) + (s2 + s3);

        // ---- next_point ----
        float grad = -Gsol;
        float proj = grad - bsum32u(grad) * 0.03125f;

        float tm1 = (proj < 0.0f) ? (-sol / proj) : INFINITY;
        float tm2 = (proj > 0.0f) ? ((1.0f - sol) / proj) : INFINITY;
        float m1 = bmin32u((tm1 > 1e-7f) ? tm1 : INFINITY);
        float m2 = bmin32u((tm2 > 1e-7f) ? tm2 : INFINITY);
        float t = __builtin_isinf(m1) ? 1.0f : m1;
        t = fminf(t, m2);
        float nxt = fmaf(proj, t, sol);

        // ---- simplex projection via rank-select (no sort) ----
        // ascending sortable key for nxt; tiebreak by lane (stable)
        int nb = __float_as_int(nxt);
        unsigned int u = (unsigned int)nb ^ ((nb < 0) ? 0xFFFFFFFFu : 0x80000000u);
        unsigned long long Ki = ((unsigned long long)u << 6)
                              | (unsigned long long)(63 - lane);

        // rank_i = #{j in 0..31 : K_j > K_i}  (descending-sort position)
        // S_i    = sum of values sort-above mine = cumsum[rank_i - 1]
        int rank = 0;
        float S = 0.0f;
#pragma unroll
        for (int j = 0; j < 32; j++) {
            unsigned int uj = (unsigned int)__builtin_amdgcn_readlane((int)u, j);
            float vj = rdlane(nxt, j);
            unsigned long long Kj = ((unsigned long long)uj << 6)
                                  | (unsigned long long)(63 - j);
            bool gt = Kj > Ki;
            rank += gt ? 1 : 0;
            S += gt ? vj : 0.0f;
        }
        float total = bsum32u(nxt);  // cumsum[31] (order differs by ~ulp)

        // cond at k = rank-1: tmp_max[k] = (S-1)/rank  >  s[k+1] = nxt_i
        float cand = (S - 1.0f) / (float)rank;          // NaN/inf ok if rank==0
        bool cond = (rank >= 1) && (cand > nxt);
        unsigned long long P =
            ((unsigned long long)(cond ? (unsigned)rank : 0xFFu) << 32)
            | (unsigned int)__float_as_int(cand);
        unsigned long long M = bminu64(P);              // min rank among cond-true
        float tmax = ((unsigned int)(M >> 32) == 0xFFu)
                   ? (total - 1.0f) * 0.03125f
                   : __int_as_float((int)(unsigned int)M);
        float newp = fmaxf(nxt - tmax, 0.0f);
        if (lane >= NT) newp = 0.0f;

        // Gn = G @ newp
        float n0 = 0, n1 = 0, n2 = 0, n3 = 0;
#pragma unroll
        for (int k = 0; k < NT; k += 4) {
            n0 = fmaf(Grow[k + 0], rdlane(newp, k + 0), n0);
            n1 = fmaf(Grow[k + 1], rdlane(newp, k + 1), n1);
            n2 = fmaf(Grow[k + 2], rdlane(newp, k + 2), n2);
            n3 = fmaf(Grow[k + 3], rdlane(newp, k + 3), n3);
        }
        float Gn = (n0 + n1) + (n2 + n3);

        float v11 = bsum32u(sol * Gsol);
        float v12 = bsum32u(sol * Gn);
        float v22 = bsum32u(newp * Gn);

        float g = (v22 - v12) / (v11 + v22 - 2.0f * v12 + EPSF);
        float gamma = (v12 >= v22) ? 0.0f : g;
        gamma = (v12 >= v11) ? 1.0f : gamma;

        float new_sol = gamma * sol + (1.0f - gamma) * newp;
        float diff = bsum32u(fabsf(new_sol - sol));
        if (diff < 1e-6f) break;   // freeze: output the OLD sol (ref semantics)
        sol = new_sol;
    }
    if (lane < NT) out[lane] = sol;
}

extern "C" void kernel_launch(void* const* d_in, const int* in_sizes, int n_in,
                              void* d_out, int out_size, void* d_ws, size_t ws_size,
                              hipStream_t stream) {
    const float* vecs = (const float*)d_in[0];
    float* out = (float*)d_out;
    double* Gd = (double*)d_ws;          // 1024 doubles = 8 KB
    const int D = in_sizes[0] / NT;      // 2097152

    hipMemsetAsync(Gd, 0, NT * NT * sizeof(double), stream);

    const int cols_per_block = WAVES_PB * TILES_PW * TILE_COLS;  // 2048
    const int grid = D / cols_per_block;                          // 1024
    gram_kernel<<<grid, GR_THREADS, 0, stream>>>(vecs, Gd, D);
    solver_kernel<<<1, 64, 0, stream>>>(Gd, out);
}

// Round 4
// 433.300 us; speedup vs baseline: 1.5205x; 1.5205x over previous
//
#include <hip/hip_runtime.h>

#define NT 32
#define EPSF 1e-8f

// ================= Gram kernel =================
// G = vecs @ vecs^T, vecs (32, D) fp32 row-major.
// Staging (round-4): NO register prefetch (rounds 2/3 spilled ~500MB scratch:
// 32 scalar loads kept 32 vaddr pairs + pre[32] live -> demand ~190 VGPR).
// Instead: 8 groups of (4 scalar loads -> 1 ds_write_b128), row base written
// as vecs + (size_t)r*D (wave-uniform -> SGPR base) + 32-bit lane offset so
// the compiler emits global_load_dword v, voff, s[base]. Live regs ~95.
// Latency hiding via TLP: grid 1024 = 4 blocks/CU x 4 waves = 16 waves/CU.
// LDS layout (validated conflict-free in r2/r3: SQ_LDS_BANK_CONFLICT=0):
// column-major swizzled, addr(r, col) = col*32 + ((r>>2) ^ (col&7))*4 + (r&3).
#define TILE_COLS 64
#define GR_THREADS 256
#define WAVES_PB 4
#define TILES_PW 8    // cols/wave = 512, cols/block = 2048 -> grid = 1024

__global__ __launch_bounds__(GR_THREADS, 2)
void gram_kernel(const float* __restrict__ vecs, double* __restrict__ Gd, int D)
{
    __shared__ __align__(16) float tile[WAVES_PB][TILE_COLS * 32];
    __shared__ float Gpart[NT * NT];

    const int tid  = threadIdx.x;
    const int wave = tid >> 6;
    const int lane = tid & 63;

    for (int e = tid; e < NT * NT; e += GR_THREADS) Gpart[e] = 0.0f;
    __syncthreads();

    float* my = tile[wave];
    const int swz = lane & 7;

    const int cj = lane >> 4;        // column subgroup 0..3
    const int pi = (lane >> 2) & 3;  // patch rows 8*pi..
    const int pk = lane & 3;         // patch cols 8*pk..

    float acc[8][8];
#pragma unroll
    for (int r = 0; r < 8; r++)
#pragma unroll
        for (int c = 0; c < 8; c++) acc[r][c] = 0.0f;

    // 32-bit lane-dependent column offset; row base stays an SGPR pair.
    const unsigned base0 = (unsigned)blockIdx.x * (WAVES_PB * TILES_PW * TILE_COLS)
                         + (unsigned)wave * (TILES_PW * TILE_COLS) + (unsigned)lane;

    for (int t = 0; t < TILES_PW; t++) {
        const unsigned off = base0 + (unsigned)t * TILE_COLS;
        // stage tile t: 8 x (4 uniform-row loads -> 1 swizzled b128 write)
#pragma unroll
        for (int g = 0; g < 8; g++) {
            const float* r0 = vecs + (size_t)(4 * g + 0) * (size_t)D;
            const float* r1 = vecs + (size_t)(4 * g + 1) * (size_t)D;
            const float* r2 = vecs + (size_t)(4 * g + 2) * (size_t)D;
            const float* r3 = vecs + (size_t)(4 * g + 3) * (size_t)D;
            float4 w = make_float4(r0[off], r1[off], r2[off], r3[off]);
            *(float4*)(my + lane * 32 + ((g ^ swz) << 2)) = w;
        }
        // per-wave DS ops are in-order; no barrier needed (wave-private tile)
#pragma unroll
        for (int jt = 0; jt < 16; jt++) {
            const int j = (jt << 2) + cj;
            const float* col = my + j * 32;
            const int js = j & 7;
            const float4 a0 = *(const float4*)(col + (((2 * pi) ^ js) << 2));
            const float4 a1 = *(const float4*)(col + (((2 * pi + 1) ^ js) << 2));
            const float4 b0 = *(const float4*)(col + (((2 * pk) ^ js) << 2));
            const float4 b1 = *(const float4*)(col + (((2 * pk + 1) ^ js) << 2));
            const float a[8] = {a0.x, a0.y, a0.z, a0.w, a1.x, a1.y, a1.z, a1.w};
            const float b[8] = {b0.x, b0.y, b0.z, b0.w, b1.x, b1.y, b1.z, b1.w};
#pragma unroll
            for (int r = 0; r < 8; r++)
#pragma unroll
                for (int c = 0; c < 8; c++)
                    acc[r][c] = fmaf(a[r], b[c], acc[r][c]);
        }
    }

    // fold the cj column-split (lanes sharing lane&15 share a patch)
#pragma unroll
    for (int r = 0; r < 8; r++)
#pragma unroll
        for (int c = 0; c < 8; c++) {
            float v = acc[r][c];
            v += __shfl_xor(v, 16);
            v += __shfl_xor(v, 32);
            if (lane < 16)
                atomicAdd(&Gpart[(8 * pi + r) * NT + (8 * pk + c)], v);
        }
    __syncthreads();
    for (int e = tid; e < NT * NT; e += GR_THREADS)
        atomicAdd(&Gd[e], (double)Gpart[e]);
}

// ================= Solver kernel =================
// Single wave; dependent-issue-latency bound -> minimize serial instruction
// count. Round-4: Gsol maintained incrementally (Gsol' = g*Gsol + (1-g)*Gn,
// exact by linearity of G) -> one matvec per iteration instead of two.
template<int CTRL>
__device__ __forceinline__ float dpp0(float x) {  // invalid source lanes -> 0
    return __int_as_float(__builtin_amdgcn_update_dpp(
        0, __float_as_int(x), CTRL, 0xF, 0xF, true));
}
template<int CTRL>
__device__ __forceinline__ float dppk(float oldv, float x) {  // invalid -> oldv
    return __int_as_float(__builtin_amdgcn_update_dpp(
        __float_as_int(oldv), __float_as_int(x), CTRL, 0xF, 0xF, false));
}
__device__ __forceinline__ float rdlane(float x, int l) {
    return __int_as_float(__builtin_amdgcn_readlane(__float_as_int(x), l));
}
__device__ __forceinline__ unsigned long long rdlane64(unsigned long long x, int l) {
    int lo = __builtin_amdgcn_readlane((int)(unsigned int)x, l);
    int hi = __builtin_amdgcn_readlane((int)(unsigned int)(x >> 32), l);
    return ((unsigned long long)(unsigned int)hi << 32) | (unsigned int)lo;
}
template<int CTRL>
__device__ __forceinline__ unsigned long long dpp64k(unsigned long long x) {
    int lo = (int)(unsigned int)x, hi = (int)(unsigned int)(x >> 32);
    int plo = __builtin_amdgcn_update_dpp(lo, lo, CTRL, 0xF, 0xF, false);
    int phi = __builtin_amdgcn_update_dpp(hi, hi, CTRL, 0xF, 0xF, false);
    return ((unsigned long long)(unsigned int)phi << 32) | (unsigned int)plo;
}

// sum over lanes 0..31, uniform result
__device__ __forceinline__ float bsum32u(float v) {
    v += dpp0<0x111>(v);  // row_shr:1
    v += dpp0<0x112>(v);  // row_shr:2
    v += dpp0<0x114>(v);  // row_shr:4
    v += dpp0<0x118>(v);  // row_shr:8
    return rdlane(v, 15) + rdlane(v, 31);
}
__device__ __forceinline__ float bmin32u(float v) {
    v = fminf(v, dppk<0x111>(v, v));
    v = fminf(v, dppk<0x112>(v, v));
    v = fminf(v, dppk<0x114>(v, v));
    v = fminf(v, dppk<0x118>(v, v));
    return fminf(rdlane(v, 15), rdlane(v, 31));
}
// min over lanes 0..31 of a packed u64, uniform result
__device__ __forceinline__ unsigned long long bminu64(unsigned long long P) {
    { unsigned long long q = dpp64k<0x111>(P); P = (q < P) ? q : P; }
    { unsigned long long q = dpp64k<0x112>(P); P = (q < P) ? q : P; }
    { unsigned long long q = dpp64k<0x114>(P); P = (q < P) ? q : P; }
    { unsigned long long q = dpp64k<0x118>(P); P = (q < P) ? q : P; }
    unsigned long long a = rdlane64(P, 0);   // min of lanes 0..15
    unsigned long long b = rdlane64(P, 16);  // min of lanes 16..31
    return (a < b) ? a : b;
}

__global__ __launch_bounds__(64)
void solver_kernel(const double* __restrict__ Gd, float* __restrict__ out)
{
    __shared__ float Gsh[NT * 33];
    const int lane = threadIdx.x;  // one wave

    for (int t2 = 0; t2 < 16; t2++) {
        int e = t2 * 64 + lane;
        Gsh[(e >> 5) * 33 + (e & 31)] = (float)Gd[e];
    }
    __syncthreads();

    float Grow[NT];
#pragma unroll
    for (int k = 0; k < NT; k++)
        Grow[k] = (lane < NT) ? Gsh[lane * 33 + k] : 0.0f;

    // ---- planar init: argmin over all 496 (a<b) pairs ----
    float bestCost = INFINITY, bestGamma = 0.0f;
    int bestEnc = 0x7FFFFFFF;
    for (int a = 0; a < NT - 1; a++) {
        int b = a + 1 + lane;
        if (b < NT) {
            float v11 = Gsh[a * 33 + a];
            float v12 = Gsh[a * 33 + b];
            float v22 = Gsh[b * 33 + b];
            float g = (v22 - v12) / (v11 + v22 - 2.0f * v12 + EPSF);
            float c = v22 + g * (v12 - v22);
            float gamma = (v12 >= v22) ? 0.0f : g;
            float cost  = (v12 >= v22) ? v22 : c;
            if (v12 >= v11) { gamma = 1.0f; cost = v11; }
            int enc = a * NT + b;
            if (cost < bestCost) { bestCost = cost; bestEnc = enc; bestGamma = gamma; }
        }
    }
#pragma unroll
    for (int m = 1; m < 64; m <<= 1) {
        float oc = __shfl_xor(bestCost, m);
        int   oe = __shfl_xor(bestEnc, m);
        float og = __shfl_xor(bestGamma, m);
        if (oc < bestCost || (oc == bestCost && oe < bestEnc)) {
            bestCost = oc; bestEnc = oe; bestGamma = og;
        }
    }
    const int bi = bestEnc >> 5, bj = bestEnc & 31;

    float sol = 0.0f;
    if (lane == bi) sol = bestGamma;
    if (lane == bj) sol = 1.0f - bestGamma;

    // initial Gsol = G @ sol (full matvec, once)
    float Gsol;
    {
        float s0 = 0, s1 = 0, s2 = 0, s3 = 0;
#pragma unroll
        for (int k = 0; k < NT; k += 4) {
            s0 = fmaf(Grow[k + 0], rdlane(sol, k + 0), s0);
            s1 = fmaf(Grow[k + 1], rdlane(sol, k + 1), s1);
            s2 = fmaf(Grow[k + 2], rdlane(sol, k + 2), s2);
            s3 = fmaf(Grow[k + 3], rdlane(sol, k + 3), s3);
        }
        Gsol = (s0 + s1) + (s2 + s3);
    }

    for (int it = 0; it < 250; it++) {
        // ---- next_point ----
        float grad = -Gsol;
        float proj = grad - bsum32u(grad) * 0.03125f;

        float tm1 = (proj < 0.0f) ? (-sol / proj) : INFINITY;
        float tm2 = (proj > 0.0f) ? ((1.0f - sol) / proj) : INFINITY;
        float m1 = bmin32u((tm1 > 1e-7f) ? tm1 : INFINITY);
        float m2 = bmin32u((tm2 > 1e-7f) ? tm2 : INFINITY);
        float t = __builtin_isinf(m1) ? 1.0f : m1;
        t = fminf(t, m2);
        float nxt = fmaf(proj, t, sol);

        // ---- simplex projection via rank-select (no sort) ----
        int nb = __float_as_int(nxt);
        unsigned int u = (unsigned int)nb ^ ((nb < 0) ? 0xFFFFFFFFu : 0x80000000u);
        unsigned long long Ki = ((unsigned long long)u << 6)
                              | (unsigned long long)(63 - lane);

        int rank = 0;
        float S = 0.0f;
#pragma unroll
        for (int j = 0; j < 32; j++) {
            unsigned int uj = (unsigned int)__builtin_amdgcn_readlane((int)u, j);
            float vj = rdlane(nxt, j);
            unsigned long long Kj = ((unsigned long long)uj << 6)
                                  | (unsigned long long)(63 - j);
            bool gt = Kj > Ki;
            rank += gt ? 1 : 0;
            S += gt ? vj : 0.0f;
        }
        float total = bsum32u(nxt);

        float cand = (S - 1.0f) / (float)rank;
        bool cond = (rank >= 1) && (cand > nxt);
        unsigned long long P =
            ((unsigned long long)(cond ? (unsigned)rank : 0xFFu) << 32)
            | (unsigned int)__float_as_int(cand);
        unsigned long long M = bminu64(P);
        float tmax = ((unsigned int)(M >> 32) == 0xFFu)
                   ? (total - 1.0f) * 0.03125f
                   : __int_as_float((int)(unsigned int)M);
        float newp = fmaxf(nxt - tmax, 0.0f);
        if (lane >= NT) newp = 0.0f;

        // Gn = G @ newp (the only matvec in the loop)
        float n0 = 0, n1 = 0, n2 = 0, n3 = 0;
#pragma unroll
        for (int k = 0; k < NT; k += 4) {
            n0 = fmaf(Grow[k + 0], rdlane(newp, k + 0), n0);
            n1 = fmaf(Grow[k + 1], rdlane(newp, k + 1), n1);
            n2 = fmaf(Grow[k + 2], rdlane(newp, k + 2), n2);
            n3 = fmaf(Grow[k + 3], rdlane(newp, k + 3), n3);
        }
        float Gn = (n0 + n1) + (n2 + n3);

        float v11 = bsum32u(sol * Gsol);
        float v12 = bsum32u(sol * Gn);
        float v22 = bsum32u(newp * Gn);

        float g = (v22 - v12) / (v11 + v22 - 2.0f * v12 + EPSF);
        float gamma = (v12 >= v22) ? 0.0f : g;
        gamma = (v12 >= v11) ? 1.0f : gamma;

        float new_sol = gamma * sol + (1.0f - gamma) * newp;
        float diff = bsum32u(fabsf(new_sol - sol));
        if (diff < 1e-6f) break;   // freeze: output the OLD sol (ref semantics)
        sol = new_sol;
        Gsol = fmaf(gamma, Gsol - Gn, Gn);   // = gamma*Gsol + (1-gamma)*Gn
    }
    if (lane < NT) out[lane] = sol;
}

extern "C" void kernel_launch(void* const* d_in, const int* in_sizes, int n_in,
                              void* d_out, int out_size, void* d_ws, size_t ws_size,
                              hipStream_t stream) {
    const float* vecs = (const float*)d_in[0];
    float* out = (float*)d_out;
    double* Gd = (double*)d_ws;          // 1024 doubles = 8 KB
    const int D = in_sizes[0] / NT;      // 2097152

    hipMemsetAsync(Gd, 0, NT * NT * sizeof(double), stream);

    const int cols_per_block = WAVES_PB * TILES_PW * TILE_COLS;  // 2048
    const int grid = D / cols_per_block;                          // 1024
    gram_kernel<<<grid, GR_THREADS, 0, stream>>>(vecs, Gd, D);
    solver_kernel<<<1, 64, 0, stream>>>(Gd, out);
}

// Round 5
// 408.924 us; speedup vs baseline: 1.6112x; 1.0596x over previous
//
#include <hip/hip_runtime.h>

#define NT 32
#define EPSF 1e-8f

// ================= Gram kernel =================
// G = vecs @ vecs^T, vecs (32, D) fp32 row-major.
// Round-5 = round-4 addressing (row base = vecs + (size_t)r*D stays a
// wave-uniform SGPR pair, lane offset one 32-bit VGPR -> no 64-bit per-lane
// vaddr pairs; r4 evidence: 84 VGPR, WRITE_SIZE 8MB = no spill)
// + round-1 software pipeline (pre[32] prefetch of tile t+1 issued before the
// compute of tile t, so ~2000cyc of FMA hides the global-load latency;
// r4 without prefetch was latency-bound at 172us, VALUBusy 19%).
// LDS: column-major swizzled, addr(r,col) = col*32 + ((r>>2)^(col&7))*4 + (r&3)
// (validated conflict-free: SQ_LDS_BANK_CONFLICT=0 in r2-r4).
// __launch_bounds__(256,1): do NOT cap registers -- a forced cap caused the
// r2/r3 ~500MB scratch-spill disaster. Expected usage ~116 VGPR -> 4 waves/SIMD.
#define TILE_COLS 64
#define GR_THREADS 256
#define WAVES_PB 4
#define TILES_PW 8    // cols/wave = 512, cols/block = 2048 -> grid = 1024

__global__ __launch_bounds__(GR_THREADS, 1)
void gram_kernel(const float* __restrict__ vecs, double* __restrict__ Gd, int D)
{
    __shared__ __align__(16) float tile[WAVES_PB][TILE_COLS * 32];
    __shared__ float Gpart[NT * NT];

    const int tid  = threadIdx.x;
    const int wave = tid >> 6;
    const int lane = tid & 63;

    for (int e = tid; e < NT * NT; e += GR_THREADS) Gpart[e] = 0.0f;
    __syncthreads();

    float* my = tile[wave];
    const int swz = lane & 7;

    const int cj = lane >> 4;        // column subgroup 0..3
    const int pi = (lane >> 2) & 3;  // patch rows 8*pi..
    const int pk = lane & 3;         // patch cols 8*pk..

    float acc[8][8];
#pragma unroll
    for (int r = 0; r < 8; r++)
#pragma unroll
        for (int c = 0; c < 8; c++) acc[r][c] = 0.0f;

    const unsigned base0 = (unsigned)blockIdx.x * (WAVES_PB * TILES_PW * TILE_COLS)
                         + (unsigned)wave * (TILES_PW * TILE_COLS) + (unsigned)lane;

    // prefetch tile 0 (SGPR row bases + one 32-bit lane offset)
    float pre[32];
#pragma unroll
    for (int r = 0; r < 32; r++)
        pre[r] = (vecs + (size_t)r * (size_t)D)[base0];

    for (int t = 0; t < TILES_PW; t++) {
        // stage tile t from pre[]: 8 swizzled b128 writes
#pragma unroll
        for (int g = 0; g < 8; g++) {
            float4 w = make_float4(pre[4 * g + 0], pre[4 * g + 1],
                                   pre[4 * g + 2], pre[4 * g + 3]);
            *(float4*)(my + lane * 32 + ((g ^ swz) << 2)) = w;
        }
        // prefetch tile t+1; loads fly during the compute below
        if (t + 1 < TILES_PW) {
            const unsigned off = base0 + (unsigned)(t + 1) * TILE_COLS;
#pragma unroll
            for (int r = 0; r < 32; r++)
                pre[r] = (vecs + (size_t)r * (size_t)D)[off];
        }
        // compute on tile t (per-wave DS ops are in-order; no barrier needed)
#pragma unroll
        for (int jt = 0; jt < 16; jt++) {
            const int j = (jt << 2) + cj;
            const float* col = my + j * 32;
            const int js = j & 7;
            const float4 a0 = *(const float4*)(col + (((2 * pi) ^ js) << 2));
            const float4 a1 = *(const float4*)(col + (((2 * pi + 1) ^ js) << 2));
            const float4 b0 = *(const float4*)(col + (((2 * pk) ^ js) << 2));
            const float4 b1 = *(const float4*)(col + (((2 * pk + 1) ^ js) << 2));
            const float a[8] = {a0.x, a0.y, a0.z, a0.w, a1.x, a1.y, a1.z, a1.w};
            const float b[8] = {b0.x, b0.y, b0.z, b0.w, b1.x, b1.y, b1.z, b1.w};
#pragma unroll
            for (int r = 0; r < 8; r++)
#pragma unroll
                for (int c = 0; c < 8; c++)
                    acc[r][c] = fmaf(a[r], b[c], acc[r][c]);
        }
    }

    // fold the cj column-split (lanes sharing lane&15 share a patch)
#pragma unroll
    for (int r = 0; r < 8; r++)
#pragma unroll
        for (int c = 0; c < 8; c++) {
            float v = acc[r][c];
            v += __shfl_xor(v, 16);
            v += __shfl_xor(v, 32);
            if (lane < 16)
                atomicAdd(&Gpart[(8 * pi + r) * NT + (8 * pk + c)], v);
        }
    __syncthreads();
    for (int e = tid; e < NT * NT; e += GR_THREADS)
        atomicAdd(&Gd[e], (double)Gpart[e]);
}

// ================= Solver kernel =================
// Single wave, dependent-issue-latency bound. Round-5: every per-element value
// is MIRRORED across the two 32-lane halves (lane l and l+32 carry element
// l&31 through identical arithmetic). The three O(32) serial loops (rank/S,
// Gsol matvec, Gn matvec) are half-split: lower half covers k/j in [0,16),
// upper half [16,32), combined with one __shfl_xor(x,32).
template<int CTRL>
__device__ __forceinline__ float dpp0(float x) {  // invalid source lanes -> 0
    return __int_as_float(__builtin_amdgcn_update_dpp(
        0, __float_as_int(x), CTRL, 0xF, 0xF, true));
}
template<int CTRL>
__device__ __forceinline__ float dppk(float oldv, float x) {  // invalid -> oldv
    return __int_as_float(__builtin_amdgcn_update_dpp(
        __float_as_int(oldv), __float_as_int(x), CTRL, 0xF, 0xF, false));
}
__device__ __forceinline__ float rdlane(float x, int l) {
    return __int_as_float(__builtin_amdgcn_readlane(__float_as_int(x), l));
}
__device__ __forceinline__ unsigned long long rdlane64(unsigned long long x, int l) {
    int lo = __builtin_amdgcn_readlane((int)(unsigned int)x, l);
    int hi = __builtin_amdgcn_readlane((int)(unsigned int)(x >> 32), l);
    return ((unsigned long long)(unsigned int)hi << 32) | (unsigned int)lo;
}
template<int CTRL>
__device__ __forceinline__ unsigned long long dpp64k(unsigned long long x) {
    int lo = (int)(unsigned int)x, hi = (int)(unsigned int)(x >> 32);
    int plo = __builtin_amdgcn_update_dpp(lo, lo, CTRL, 0xF, 0xF, false);
    int phi = __builtin_amdgcn_update_dpp(hi, hi, CTRL, 0xF, 0xF, false);
    return ((unsigned long long)(unsigned int)phi << 32) | (unsigned int)plo;
}

// sum over lanes 0..31, uniform (row_shr chain leaves mins/sums at 15 & 31)
__device__ __forceinline__ float bsum32u(float v) {
    v += dpp0<0x111>(v);
    v += dpp0<0x112>(v);
    v += dpp0<0x114>(v);
    v += dpp0<0x118>(v);
    return rdlane(v, 15) + rdlane(v, 31);
}
__device__ __forceinline__ float bmin32u(float v) {
    v = fminf(v, dppk<0x111>(v, v));
    v = fminf(v, dppk<0x112>(v, v));
    v = fminf(v, dppk<0x114>(v, v));
    v = fminf(v, dppk<0x118>(v, v));
    return fminf(rdlane(v, 15), rdlane(v, 31));
}
// min over lanes 0..31 of a packed u64, uniform
// (FIXED r5: row_shr leaves row-minima at lanes 15/31, not 0/16)
__device__ __forceinline__ unsigned long long bminu64(unsigned long long P) {
    { unsigned long long q = dpp64k<0x111>(P); P = (q < P) ? q : P; }
    { unsigned long long q = dpp64k<0x112>(P); P = (q < P) ? q : P; }
    { unsigned long long q = dpp64k<0x114>(P); P = (q < P) ? q : P; }
    { unsigned long long q = dpp64k<0x118>(P); P = (q < P) ? q : P; }
    unsigned long long a = rdlane64(P, 15);
    unsigned long long b = rdlane64(P, 31);
    return (a < b) ? a : b;
}

__global__ __launch_bounds__(64)
void solver_kernel(const double* __restrict__ Gd, float* __restrict__ out)
{
    __shared__ float Gsh[NT * 33];
    __shared__ float  Tvec[64];   // broadcast table for matvec multiplier
    __shared__ float2 Tkv[64];    // (value, sort-key) pairs for rank-select

    const int lane = threadIdx.x;
    const int e = lane & 31;      // element owned (mirrored halves)
    const int h = lane >> 5;      // half: covers k/j in [16h, 16h+16)

    for (int t2 = 0; t2 < 16; t2++) {
        int idx = t2 * 64 + lane;
        Gsh[(idx >> 5) * 33 + (idx & 31)] = (float)Gd[idx];
    }
    __syncthreads();

    // lane holds G[e][16h + k], k = 0..15
    float Grow[16];
#pragma unroll
    for (int k = 0; k < 16; k++)
        Grow[k] = Gsh[e * 33 + 16 * h + k];

    // half-split matvec: y_e = sum_k G[e][k] * x_k  (uniform-mirrored result)
    auto matvec = [&](float x) -> float {
        Tvec[lane] = x;  // lanes 0..31 fill entries 0..31; upper entries unread
        float a0 = 0.0f, a1 = 0.0f;
#pragma unroll
        for (int s = 0; s < 16; s += 2) {
            a0 = fmaf(Grow[s + 0], Tvec[16 * h + s + 0], a0);
            a1 = fmaf(Grow[s + 1], Tvec[16 * h + s + 1], a1);
        }
        float half = a0 + a1;
        return half + __shfl_xor(half, 32);
    };

    // ---- planar init: argmin over all 496 (a<b) pairs ----
    float bestCost = INFINITY, bestGamma = 0.0f;
    int bestEnc = 0x7FFFFFFF;
    for (int a = 0; a < NT - 1; a++) {
        int b = a + 1 + lane;
        if (b < NT) {
            float v11 = Gsh[a * 33 + a];
            float v12 = Gsh[a * 33 + b];
            float v22 = Gsh[b * 33 + b];
            float g = (v22 - v12) / (v11 + v22 - 2.0f * v12 + EPSF);
            float c = v22 + g * (v12 - v22);
            float gamma = (v12 >= v22) ? 0.0f : g;
            float cost  = (v12 >= v22) ? v22 : c;
            if (v12 >= v11) { gamma = 1.0f; cost = v11; }
            int enc = a * NT + b;
            if (cost < bestCost) { bestCost = cost; bestEnc = enc; bestGamma = gamma; }
        }
    }
#pragma unroll
    for (int m = 1; m < 64; m <<= 1) {
        float oc = __shfl_xor(bestCost, m);
        int   oe = __shfl_xor(bestEnc, m);
        float og = __shfl_xor(bestGamma, m);
        if (oc < bestCost || (oc == bestCost && oe < bestEnc)) {
            bestCost = oc; bestEnc = oe; bestGamma = og;
        }
    }
    const int bi = bestEnc >> 5, bj = bestEnc & 31;

    float sol = 0.0f;                      // mirrored across halves
    if (e == bi) sol = bestGamma;
    if (e == bj) sol = 1.0f - bestGamma;

    for (int it = 0; it < 250; it++) {
        float Gsol = matvec(sol);          // exact (no recurrence: r4's 2.4e-4 was from it)

        // ---- next_point ----
        float grad = -Gsol;
        float proj = grad - bsum32u(grad) * 0.03125f;

        float tm1 = (proj < 0.0f) ? (-sol / proj) : INFINITY;
        float tm2 = (proj > 0.0f) ? ((1.0f - sol) / proj) : INFINITY;
        float m1 = bmin32u((tm1 > 1e-7f) ? tm1 : INFINITY);
        float m2 = bmin32u((tm2 > 1e-7f) ? tm2 : INFINITY);
        float t = __builtin_isinf(m1) ? 1.0f : m1;
        t = fminf(t, m2);
        float nxt = fmaf(proj, t, sol);

        // ---- simplex projection via half-split rank-select ----
        // key order identical to r3's u64 key (u<<6 | 63-lane):
        // Kj > Ki  <=>  (uj > ui) | (uj == ui & j < i)
        int nb = __float_as_int(nxt);
        unsigned u = (unsigned)nb ^ ((nb < 0) ? 0xFFFFFFFFu : 0x80000000u);
        Tkv[lane] = make_float2(nxt, __int_as_float((int)u));

        int rank = 0;
        float S = 0.0f;
        const int dtie = e - 16 * h;       // j < e  <=>  s < dtie (j = s+16h)
#pragma unroll
        for (int s = 0; s < 16; s++) {
            float2 kv = Tkv[16 * h + s];
            unsigned uj = (unsigned)__float_as_int(kv.y);
            bool gt = (uj > u) || ((uj == u) && (s < dtie));
            rank += gt ? 1 : 0;
            S += gt ? kv.x : 0.0f;
        }
        rank += __shfl_xor(rank, 32);      // int add: commutative, mirror-safe
        S += __shfl_xor(S, 32);            // fp add of 2: commutative bitwise

        float total = bsum32u(nxt);

        float cand = (S - 1.0f) / (float)rank;   // rank==0 -> -inf, cond false
        bool cond = (rank >= 1) && (cand > nxt);
        unsigned long long P =
            ((unsigned long long)(cond ? (unsigned)rank : 0xFFu) << 32)
            | (unsigned int)__float_as_int(cand);
        unsigned long long M = bminu64(P);
        float tmax = ((unsigned int)(M >> 32) == 0xFFu)
                   ? (total - 1.0f) * 0.03125f
                   : __int_as_float((int)(unsigned int)M);
        float newp = fmaxf(nxt - tmax, 0.0f);    // mirrored (no upper zeroing)

        float Gn = matvec(newp);

        // v11 (lower half: sol*Gsol) and v22 (upper half: newp*Gn) share one
        // reduction chain; both trees are element-ordered = bsum32u-identical.
        float z = (h == 0) ? (sol * Gsol) : (newp * Gn);
        z += dpp0<0x111>(z);
        z += dpp0<0x112>(z);
        z += dpp0<0x114>(z);
        z += dpp0<0x118>(z);
        float v11 = rdlane(z, 15) + rdlane(z, 31);
        float v22 = rdlane(z, 47) + rdlane(z, 63);
        float v12 = bsum32u(sol * Gn);

        float g = (v22 - v12) / (v11 + v22 - 2.0f * v12 + EPSF);
        float gamma = (v12 >= v22) ? 0.0f : g;
        gamma = (v12 >= v11) ? 1.0f : gamma;

        float new_sol = gamma * sol + (1.0f - gamma) * newp;
        float diff = bsum32u(fabsf(new_sol - sol));
        if (diff < 1e-6f) break;   // freeze: output the OLD sol (ref semantics)
        sol = new_sol;
    }
    if (lane < NT) out[lane] = sol;
}

extern "C" void kernel_launch(void* const* d_in, const int* in_sizes, int n_in,
                              void* d_out, int out_size, void* d_ws, size_t ws_size,
                              hipStream_t stream) {
    const float* vecs = (const float*)d_in[0];
    float* out = (float*)d_out;
    double* Gd = (double*)d_ws;          // 1024 doubles = 8 KB
    const int D = in_sizes[0] / NT;      // 2097152

    hipMemsetAsync(Gd, 0, NT * NT * sizeof(double), stream);

    const int cols_per_block = WAVES_PB * TILES_PW * TILE_COLS;  // 2048
    const int grid = D / cols_per_block;                          // 1024
    gram_kernel<<<grid, GR_THREADS, 0, stream>>>(vecs, Gd, D);
    solver_kernel<<<1, 64, 0, stream>>>(Gd, out);
}